// Round 3
// baseline (509.704 us; speedup 1.0000x reference)
//
#include <hip/hip_runtime.h>
#include <hip/hip_bf16.h>
#include <stdint.h>

// Problem: out[b,s,o] = alpha * sum_k x[b,s,k] * t[o,k],  t in {-1,0,+1}
// M = 4*2048 = 8192, K = 4096, N = 4096.
#define M_DIM 8192
#define K_DIM 4096
#define N_DIM 4096

typedef __attribute__((ext_vector_type(8))) short short8;
typedef __attribute__((ext_vector_type(4))) float f32x4;

// ---------------------------------------------------------------------------
// async global->LDS, 16B per lane (global_load_lds_dwordx4)
// ---------------------------------------------------------------------------
__device__ __forceinline__ void lds_load16(const ushort* g, ushort* l) {
    __builtin_amdgcn_global_load_lds(
        (const __attribute__((address_space(1))) uint32_t*)g,
        (__attribute__((address_space(3))) uint32_t*)l, 16, 0, 0);
}

__device__ __forceinline__ ushort f2bf_rne(float f) {
    uint32_t u = __float_as_uint(f);
    uint32_t r = (u + 0x7FFFu + ((u >> 16) & 1u)) >> 16;
    return (ushort)r;
}

// ---------------------------------------------------------------------------
// Pass 1 (fused): per-block partial sums of |w| (fp64, deterministic)
//                 + cast x fp32 -> bf16.  Grid-stride, 2048 blocks (G11/G13).
// ---------------------------------------------------------------------------
__global__ void k_prep(const float* __restrict__ w, double* __restrict__ partial,
                       const float* __restrict__ x, ushort* __restrict__ xb) {
    const int nth = gridDim.x * blockDim.x;
    const int gtid = blockIdx.x * blockDim.x + threadIdx.x;

    // --- |w| partial sum ---
    const float4* w4 = (const float4*)w;
    double s = 0.0;
    for (int i = gtid; i < (K_DIM * N_DIM) / 4; i += nth) {
        float4 v = w4[i];
        s += (double)fabsf(v.x) + (double)fabsf(v.y) + (double)fabsf(v.z) + (double)fabsf(v.w);
    }
    #pragma unroll
    for (int off = 32; off > 0; off >>= 1) s += __shfl_down(s, off, 64);
    __shared__ double sm[4];
    int lane = threadIdx.x & 63, wv = threadIdx.x >> 6;
    if (lane == 0) sm[wv] = s;
    __syncthreads();
    if (threadIdx.x == 0) partial[blockIdx.x] = sm[0] + sm[1] + sm[2] + sm[3];

    // --- x -> bf16 cast (independent work, same kernel: overlapped, 1 less launch) ---
    const float4* x4 = (const float4*)x;
    ushort4* xb4 = (ushort4*)xb;
    for (int i = gtid; i < (M_DIM * K_DIM) / 4; i += nth) {
        float4 v = x4[i];
        ushort4 o;
        o.x = f2bf_rne(v.x);
        o.y = f2bf_rne(v.y);
        o.z = f2bf_rne(v.z);
        o.w = f2bf_rne(v.w);
        xb4[i] = o;
    }
}

// Pass 1b: finalize alpha = mean(|w|) over 2048 partials
__global__ void k_alpha(const double* __restrict__ partial, float* __restrict__ alpha_out) {
    double s = 0.0;
    for (int i = threadIdx.x; i < 2048; i += 256) s += partial[i];
    #pragma unroll
    for (int off = 32; off > 0; off >>= 1) s += __shfl_down(s, off, 64);
    __shared__ double sm[4];
    int lane = threadIdx.x & 63, wv = threadIdx.x >> 6;
    if (lane == 0) sm[wv] = s;
    __syncthreads();
    if (threadIdx.x == 0) {
        double total = sm[0] + sm[1] + sm[2] + sm[3];
        alpha_out[0] = (float)(total * (1.0 / 16777216.0));
    }
}

// ---------------------------------------------------------------------------
// Pass 2: quantize w -> ternary {-1,0,+1} as bf16 (N x K row-major)
//         16 B/lane stores (2x float4 in -> ushort8 out), grid-stride.
// ---------------------------------------------------------------------------
__global__ void k_quant(const float* __restrict__ w, const float* __restrict__ alpha_p,
                        ushort* __restrict__ qw) {
    const float thr = 0.5f * alpha_p[0];
    const int nth = gridDim.x * blockDim.x;
    const int gtid = blockIdx.x * blockDim.x + threadIdx.x;
    const float4* w4 = (const float4*)w;
    short8* q8 = (short8*)qw;
    for (int i = gtid; i < (K_DIM * N_DIM) / 8; i += nth) {
        float4 a = w4[2 * i], b = w4[2 * i + 1];
        short8 o;
        o[0] = a.x > thr ? (short)0x3F80 : (a.x < -thr ? (short)0xBF80 : (short)0);
        o[1] = a.y > thr ? (short)0x3F80 : (a.y < -thr ? (short)0xBF80 : (short)0);
        o[2] = a.z > thr ? (short)0x3F80 : (a.z < -thr ? (short)0xBF80 : (short)0);
        o[3] = a.w > thr ? (short)0x3F80 : (a.w < -thr ? (short)0xBF80 : (short)0);
        o[4] = b.x > thr ? (short)0x3F80 : (b.x < -thr ? (short)0xBF80 : (short)0);
        o[5] = b.y > thr ? (short)0x3F80 : (b.y < -thr ? (short)0xBF80 : (short)0);
        o[6] = b.z > thr ? (short)0x3F80 : (b.z < -thr ? (short)0xBF80 : (short)0);
        o[7] = b.w > thr ? (short)0x3F80 : (b.w < -thr ? (short)0xBF80 : (short)0);
        q8[i] = o;
    }
}

// ---------------------------------------------------------------------------
// Pass 3: 256x256 bf16 MFMA GEMM, m201-style 4-phase/K-tile schedule.
//   BM=BN=256, BK=64, 512 threads = 8 waves (2M x 4N), per-wave C = 128x64.
//   LDS 128 KiB: [buf2][A|B][half2][128 rows x 64 ushorts], T2 XOR swizzle
//   (slot = chunk ^ (row&7)) on BOTH pre-swizzled gload source and ds_read.
//   DISTANCE-2 staging (this round's change): P3 stages B(t+2) (both halves),
//   P4 stages A(t+2) (both halves); tile-boundary s_waitcnt vmcnt(8) keeps the
//   8 newest loads (tile t+2) in flight and drains exactly tile t+1 — cover
//   for every load is >= 1 full K-tile (~1300 cyc) > 900-cyc HBM latency.
//   Hazards: B(t) reads drain at P2 lgkmcnt(0), all waves past P2-bar#2 before
//   any P3 SB issue; A(t) reads drain at P3 lgkmcnt(0) before P4 SA issue.
//   Tail: when t+2==NT nothing new is issued -> vmcnt(8) would be a no-op, so
//   switch to vmcnt(0) there.
// ---------------------------------------------------------------------------
#define NT (K_DIM / 64)  // 64 K-tiles

#define MFMA16(a, b, c) __builtin_amdgcn_mfma_f32_16x16x32_bf16((a), (b), (c), 0, 0, 0)

__global__ __launch_bounds__(512, 2) void k_gemm(const ushort* __restrict__ A,  // M x K bf16
                                                 const ushort* __restrict__ B,  // N x K bf16
                                                 const float* __restrict__ alpha_p,
                                                 float* __restrict__ C) {
    // 128 KiB LDS. Layout (ushort offsets): buf*32768 + isB*16384 + half*8192.
    __shared__ __align__(16) ushort lds[65536];

    const int tid = threadIdx.x;
    const int lane = tid & 63;
    const int w = tid >> 6;       // 0..7
    const int wr = w >> 2;        // 0..1  M wave-group
    const int wc = w & 3;         // 0..3  N wave-group
    const int r = lane & 15, q = lane >> 4;

    // T1: XCD-aware bijective swizzle (512 blocks, 512 % 8 == 0)
    const int wg = blockIdx.x;
    const int swz = (wg & 7) * 64 + (wg >> 3);
    const int bm = swz >> 4;      // 0..31 (M tiles)
    const int bn = swz & 15;      // 0..15 (N tiles)

    // materialize alpha before staging so the vmcnt stream stays clean
    float alpha = alpha_p[0];
    asm volatile("" :: "v"(alpha));

    const ushort* Abase = A + (size_t)bm * 256 * K_DIM;
    const ushort* Bbase = B + (size_t)bn * 256 * K_DIM;

    // staging: thread covers (row = tid>>3, slot = tid&7) of a 64-row chunk;
    // stored logical k-chunk = slot ^ (row&7)  -> pre-swizzled SOURCE address,
    // lane-linear LDS dest (rule 21).
    const int srow = tid >> 3;                // 0..63
    const int sch = (tid & 7) ^ (srow & 7);   // pre-swizzled source k-chunk

    // read: frag (row = f*16+r, logical chunk = s*4+q) lives at slot (s*4+q)^(r&7)
    const int ch0 = q ^ (r & 7);
    const int o0 = r * 64 + ch0 * 8;          // s=0 ushort offset within 16-row frag
    const int o1 = r * 64 + (ch0 ^ 4) * 8;    // s=1

    f32x4 acc[8][4] = {};   // [m-frag 0..7][n-frag 0..3]

    auto SA = [&](int h, int bb, int tt) {    // stage A half h of tile tt into buf bb
        const ushort* g = Abase + (size_t)(h * 128 + srow) * K_DIM + tt * 64 + sch * 8;
        ushort* l = lds + bb * 32768 + h * 8192 + tid * 8;
        lds_load16(g, l);
        lds_load16(g + (size_t)64 * K_DIM, l + 4096);
    };
    auto SB = [&](int h, int bb, int tt) {
        const ushort* g = Bbase + (size_t)(h * 128 + srow) * K_DIM + tt * 64 + sch * 8;
        ushort* l = lds + bb * 32768 + 16384 + h * 8192 + tid * 8;
        lds_load16(g, l);
        lds_load16(g + (size_t)64 * K_DIM, l + 4096);
    };

    // ---- prologue: tile0 A+B (8 loads), then B(1) (4), then A(1) (4)
    //      (issue order matches steady state: B before A)
    SA(0, 0, 0); SA(1, 0, 0); SB(0, 0, 0); SB(1, 0, 0);
    SB(0, 1, 1); SB(1, 1, 1);
    SA(0, 1, 1); SA(1, 1, 1);
    asm volatile("s_waitcnt vmcnt(8)" ::: "memory");   // tile0 landed; tile1 (8) in flight
    __builtin_amdgcn_s_barrier();

    for (int t = 0; t < NT; ++t) {
        const int b = t & 1;
        const ushort* aL = lds + b * 32768 + wr * 8192;
        const ushort* bL = lds + b * 32768 + 16384 + (wc >> 1) * 8192 + (wc & 1) * 4096;
        short8 am[4][2], b01[2][2], b23[2][2];

        // ---------------- P1: read A0(m0-3)+B01 (12 ds_read); Q(0,0)
        #pragma unroll
        for (int i = 0; i < 4; ++i) {
            am[i][0] = *(const short8*)(aL + i * 1024 + o0);
            am[i][1] = *(const short8*)(aL + i * 1024 + o1);
        }
        #pragma unroll
        for (int j = 0; j < 2; ++j) {
            b01[j][0] = *(const short8*)(bL + j * 1024 + o0);
            b01[j][1] = *(const short8*)(bL + j * 1024 + o1);
        }
        asm volatile("s_waitcnt lgkmcnt(8)" ::: "memory");   // throttle the 12-read burst
        __builtin_amdgcn_s_barrier();
        asm volatile("s_waitcnt lgkmcnt(0)" ::: "memory");
        __builtin_amdgcn_sched_barrier(0);
        __builtin_amdgcn_s_setprio(1);
        #pragma unroll
        for (int i = 0; i < 4; ++i)
            #pragma unroll
            for (int j = 0; j < 2; ++j) {
                acc[i][j] = MFMA16(am[i][0], b01[j][0], acc[i][j]);
                acc[i][j] = MFMA16(am[i][1], b01[j][1], acc[i][j]);
            }
        __builtin_amdgcn_s_setprio(0);
        __builtin_amdgcn_s_barrier();

        // ---------------- P2: read B23 (4 ds_read); Q(0,1)
        #pragma unroll
        for (int j = 0; j < 2; ++j) {
            b23[j][0] = *(const short8*)(bL + (2 + j) * 1024 + o0);
            b23[j][1] = *(const short8*)(bL + (2 + j) * 1024 + o1);
        }
        __builtin_amdgcn_s_barrier();
        asm volatile("s_waitcnt lgkmcnt(0)" ::: "memory");
        __builtin_amdgcn_sched_barrier(0);
        __builtin_amdgcn_s_setprio(1);
        #pragma unroll
        for (int i = 0; i < 4; ++i)
            #pragma unroll
            for (int j = 0; j < 2; ++j) {
                acc[i][2 + j] = MFMA16(am[i][0], b23[j][0], acc[i][2 + j]);
                acc[i][2 + j] = MFMA16(am[i][1], b23[j][1], acc[i][2 + j]);
            }
        __builtin_amdgcn_s_setprio(0);
        __builtin_amdgcn_s_barrier();

        // ---------------- P3: read A1(m4-7, 8 ds_read); stage B(t+2) both halves; Q(1,1)
        #pragma unroll
        for (int i = 0; i < 4; ++i) {
            am[i][0] = *(const short8*)(aL + (4 + i) * 1024 + o0);
            am[i][1] = *(const short8*)(aL + (4 + i) * 1024 + o1);
        }
        if (t + 2 < NT) { SB(0, b, t + 2); SB(1, b, t + 2); }  // B(t) reads drained at P2
        __builtin_amdgcn_s_barrier();
        asm volatile("s_waitcnt lgkmcnt(0)" ::: "memory");
        __builtin_amdgcn_sched_barrier(0);
        __builtin_amdgcn_s_setprio(1);
        #pragma unroll
        for (int i = 0; i < 4; ++i)
            #pragma unroll
            for (int j = 0; j < 2; ++j) {
                acc[4 + i][2 + j] = MFMA16(am[i][0], b23[j][0], acc[4 + i][2 + j]);
                acc[4 + i][2 + j] = MFMA16(am[i][1], b23[j][1], acc[4 + i][2 + j]);
            }
        __builtin_amdgcn_s_setprio(0);
        __builtin_amdgcn_s_barrier();

        // ---------------- P4: stage A(t+2) both halves; Q(1,0); vmcnt(8); barrier
        if (t + 2 < NT) { SA(0, b, t + 2); SA(1, b, t + 2); }  // A(t) reads drained at P3
        __builtin_amdgcn_s_setprio(1);
        #pragma unroll
        for (int i = 0; i < 4; ++i)
            #pragma unroll
            for (int j = 0; j < 2; ++j) {
                acc[4 + i][j] = MFMA16(am[i][0], b01[j][0], acc[4 + i][j]);
                acc[4 + i][j] = MFMA16(am[i][1], b01[j][1], acc[4 + i][j]);
            }
        __builtin_amdgcn_s_setprio(0);
        // drain tile t+1 (the 8 oldest); keep tile t+2's 8 loads in flight
        if (t + 2 < NT) asm volatile("s_waitcnt vmcnt(8)" ::: "memory");
        else            asm volatile("s_waitcnt vmcnt(0)" ::: "memory");
        __builtin_amdgcn_s_barrier();
    }

    // ---- epilogue: C/D layout col = lane&15, row = (lane>>4)*4 + reg  [m89]
    const int row0 = bm * 256 + wr * 128 + q * 4;
    const int col0 = bn * 256 + wc * 64 + r;
    #pragma unroll
    for (int i = 0; i < 8; ++i)
        #pragma unroll
        for (int j = 0; j < 4; ++j)
            #pragma unroll
            for (int v = 0; v < 4; ++v)
                C[(size_t)(row0 + i * 16 + v) * N_DIM + col0 + j * 16] = alpha * acc[i][j][v];
}

// ---------------------------------------------------------------------------
extern "C" void kernel_launch(void* const* d_in, const int* in_sizes, int n_in,
                              void* d_out, int out_size, void* d_ws, size_t ws_size,
                              hipStream_t stream) {
    const float* x = (const float*)d_in[0];  // 4*2048*4096 fp32
    const float* w = (const float*)d_in[1];  // 4096*4096 fp32
    float* out = (float*)d_out;              // 8192*4096 fp32

    char* ws = (char*)d_ws;
    double* partial = (double*)ws;                           // 16 KB (2048 doubles)
    float* alpha = (float*)(ws + 16384);                     // 4 B
    ushort* qw = (ushort*)(ws + 32768);                      // 32 MB (N x K bf16 ternary)
    ushort* xb = (ushort*)(ws + 32768 + (size_t)K_DIM * N_DIM * 2);  // 64 MB (M x K bf16)

    k_prep<<<2048, 256, 0, stream>>>(w, partial, x, xb);
    k_alpha<<<1, 256, 0, stream>>>(partial, alpha);
    k_quant<<<2048, 256, 0, stream>>>(w, alpha, qw);

    // 256x256 tiles: (8192/256)*(4096/256) = 32*16 = 512 blocks of 512 threads
    k_gemm<<<512, 512, 0, stream>>>(xb, qw, alpha, out);
}

// Round 4
// 505.646 us; speedup vs baseline: 1.0080x; 1.0080x over previous
//
#include <hip/hip_runtime.h>
#include <hip/hip_bf16.h>
#include <stdint.h>

// Problem: out[b,s,o] = alpha * sum_k x[b,s,k] * t[o,k],  t in {-1,0,+1}
// M = 4*2048 = 8192, K = 4096, N = 4096.
#define M_DIM 8192
#define K_DIM 4096
#define N_DIM 4096

typedef __attribute__((ext_vector_type(8))) short short8;
typedef __attribute__((ext_vector_type(4))) float f32x4;

// ---------------------------------------------------------------------------
// async global->LDS, 16B per lane (global_load_lds_dwordx4)
// ---------------------------------------------------------------------------
__device__ __forceinline__ void lds_load16(const ushort* g, ushort* l) {
    __builtin_amdgcn_global_load_lds(
        (const __attribute__((address_space(1))) uint32_t*)g,
        (__attribute__((address_space(3))) uint32_t*)l, 16, 0, 0);
}

__device__ __forceinline__ ushort f2bf_rne(float f) {
    uint32_t u = __float_as_uint(f);
    uint32_t r = (u + 0x7FFFu + ((u >> 16) & 1u)) >> 16;
    return (ushort)r;
}

// ---------------------------------------------------------------------------
// Pass 1 (fused): per-block partial sums of |w| (fp64, deterministic)
//                 + cast x fp32 -> bf16.  Grid-stride, 2048 blocks.
// ---------------------------------------------------------------------------
__global__ void k_prep(const float* __restrict__ w, double* __restrict__ partial,
                       const float* __restrict__ x, ushort* __restrict__ xb) {
    const int nth = gridDim.x * blockDim.x;
    const int gtid = blockIdx.x * blockDim.x + threadIdx.x;

    const float4* w4 = (const float4*)w;
    double s = 0.0;
    for (int i = gtid; i < (K_DIM * N_DIM) / 4; i += nth) {
        float4 v = w4[i];
        s += (double)fabsf(v.x) + (double)fabsf(v.y) + (double)fabsf(v.z) + (double)fabsf(v.w);
    }
    #pragma unroll
    for (int off = 32; off > 0; off >>= 1) s += __shfl_down(s, off, 64);
    __shared__ double sm[4];
    int lane = threadIdx.x & 63, wv = threadIdx.x >> 6;
    if (lane == 0) sm[wv] = s;
    __syncthreads();
    if (threadIdx.x == 0) partial[blockIdx.x] = sm[0] + sm[1] + sm[2] + sm[3];

    const float4* x4 = (const float4*)x;
    ushort4* xb4 = (ushort4*)xb;
    for (int i = gtid; i < (M_DIM * K_DIM) / 4; i += nth) {
        float4 v = x4[i];
        ushort4 o;
        o.x = f2bf_rne(v.x);
        o.y = f2bf_rne(v.y);
        o.z = f2bf_rne(v.z);
        o.w = f2bf_rne(v.w);
        xb4[i] = o;
    }
}

// Pass 1b: finalize alpha = mean(|w|) over 2048 partials
__global__ void k_alpha(const double* __restrict__ partial, float* __restrict__ alpha_out) {
    double s = 0.0;
    for (int i = threadIdx.x; i < 2048; i += 256) s += partial[i];
    #pragma unroll
    for (int off = 32; off > 0; off >>= 1) s += __shfl_down(s, off, 64);
    __shared__ double sm[4];
    int lane = threadIdx.x & 63, wv = threadIdx.x >> 6;
    if (lane == 0) sm[wv] = s;
    __syncthreads();
    if (threadIdx.x == 0) {
        double total = sm[0] + sm[1] + sm[2] + sm[3];
        alpha_out[0] = (float)(total * (1.0 / 16777216.0));
    }
}

// ---------------------------------------------------------------------------
// Pass 2: quantize w -> ternary {-1,0,+1} as bf16 (N x K row-major)
// ---------------------------------------------------------------------------
__global__ void k_quant(const float* __restrict__ w, const float* __restrict__ alpha_p,
                        ushort* __restrict__ qw) {
    const float thr = 0.5f * alpha_p[0];
    const int nth = gridDim.x * blockDim.x;
    const int gtid = blockIdx.x * blockDim.x + threadIdx.x;
    const float4* w4 = (const float4*)w;
    short8* q8 = (short8*)qw;
    for (int i = gtid; i < (K_DIM * N_DIM) / 8; i += nth) {
        float4 a = w4[2 * i], b = w4[2 * i + 1];
        short8 o;
        o[0] = a.x > thr ? (short)0x3F80 : (a.x < -thr ? (short)0xBF80 : (short)0);
        o[1] = a.y > thr ? (short)0x3F80 : (a.y < -thr ? (short)0xBF80 : (short)0);
        o[2] = a.z > thr ? (short)0x3F80 : (a.z < -thr ? (short)0xBF80 : (short)0);
        o[3] = a.w > thr ? (short)0x3F80 : (a.w < -thr ? (short)0xBF80 : (short)0);
        o[4] = b.x > thr ? (short)0x3F80 : (b.x < -thr ? (short)0xBF80 : (short)0);
        o[5] = b.y > thr ? (short)0x3F80 : (b.y < -thr ? (short)0xBF80 : (short)0);
        o[6] = b.z > thr ? (short)0x3F80 : (b.z < -thr ? (short)0xBF80 : (short)0);
        o[7] = b.w > thr ? (short)0x3F80 : (b.w < -thr ? (short)0xBF80 : (short)0);
        q8[i] = o;
    }
}

// ---------------------------------------------------------------------------
// Pass 3: 256x256 bf16 MFMA GEMM with READ-AHEAD software pipeline.
//   BM=BN=256, BK=64, 512 threads = 8 waves (2M x 4N), per-wave C = 128x64.
//   LDS 128 KiB double-buffered, T2 XOR swizzle (slot = chunk ^ (row&7)) on
//   both the pre-swizzled gload source and the ds_read address (rule 21).
//
//   ROUND-4 CHANGE: fragment ds_reads are issued ONE PHASE AHEAD of their
//   MFMA use, so the LDS drain (~200-400cyc/phase) overlaps the matrix-pipe
//   backlog (~620cyc/phase) instead of serializing with it (rounds 2/3 paid
//   lgkmcnt(0) on same-phase reads => full LDS+MFMA serialization, 46% util).
//   Read schedule (tile t): P1 issues b23(t); P2 issues amB(t) [A-half-1];
//   P3 issues amA(t+1) from buf^1; P4 (after Q4) issues b01(t+1).
//   Register-reuse windows verified: every reload follows the old value's
//   last MFMA in program order - no ping-pong regs needed (stays <256 regs).
//   All LDS waits are compiler-counted (HIP-level reads). Manual waits only
//   for gload_lds (vmcnt): boundary vmcnt(0) at P2-end drains tile t+1's
//   staging, which was issued 1.5 tiles (~4000cyc) earlier - free wait.
//   Staging (distance-2): P3 stages B(t+2) after P2-bar (all waves' B-reads
//   of buf b drained by their pre-Q2 waits); P4 stages A(t+2) after P3-bar
//   (A-reads drained by pre-Q3 waits). buf^1 reads only after vmcnt(0)+bar.
//   4 barriers/tile, all wave-uniform.
// ---------------------------------------------------------------------------
#define NT (K_DIM / 64)  // 64 K-tiles

#define MFMA16(a, b, c) __builtin_amdgcn_mfma_f32_16x16x32_bf16((a), (b), (c), 0, 0, 0)

__global__ __launch_bounds__(512, 2) void k_gemm(const ushort* __restrict__ A,  // M x K bf16
                                                 const ushort* __restrict__ B,  // N x K bf16
                                                 const float* __restrict__ alpha_p,
                                                 float* __restrict__ C) {
    // 128 KiB LDS. Layout (ushort offsets): buf*32768 + isB*16384 + half*8192.
    __shared__ __align__(16) ushort lds[65536];

    const int tid = threadIdx.x;
    const int lane = tid & 63;
    const int w = tid >> 6;       // 0..7
    const int wr = w >> 2;        // 0..1  M wave-group
    const int wc = w & 3;         // 0..3  N wave-group
    const int r = lane & 15, q = lane >> 4;

    // T1: XCD-aware bijective swizzle (512 blocks, 512 % 8 == 0)
    const int wg = blockIdx.x;
    const int swz = (wg & 7) * 64 + (wg >> 3);
    const int bm = swz >> 4;      // 0..31 (M tiles)
    const int bn = swz & 15;      // 0..15 (N tiles)

    float alpha = alpha_p[0];
    asm volatile("" :: "v"(alpha));

    const ushort* Abase = A + (size_t)bm * 256 * K_DIM;
    const ushort* Bbase = B + (size_t)bn * 256 * K_DIM;

    // staging: thread covers (row = tid>>3, slot = tid&7); stored logical
    // k-chunk = slot ^ (row&7) -> pre-swizzled SOURCE, lane-linear LDS dest.
    const int srow = tid >> 3;
    const int sch = (tid & 7) ^ (srow & 7);

    // read: frag (row = f*16+r, logical chunk = s*4+q) at slot (s*4+q)^(r&7)
    const int ch0 = q ^ (r & 7);
    const int o0 = r * 64 + ch0 * 8;
    const int o1 = r * 64 + (ch0 ^ 4) * 8;

    f32x4 acc[8][4] = {};           // [m-frag][n-frag]
    short8 amA[4][2], amB[4][2];    // A half-0 / half-1 fragments (this wave)
    short8 b01[2][2], b23[2][2];    // B n-frags 0-1 / 2-3

    auto SA = [&](int h, int bb, int tt) {
        const ushort* g = Abase + (size_t)(h * 128 + srow) * K_DIM + tt * 64 + sch * 8;
        ushort* l = lds + bb * 32768 + h * 8192 + tid * 8;
        lds_load16(g, l);
        lds_load16(g + (size_t)64 * K_DIM, l + 4096);
    };
    auto SB = [&](int h, int bb, int tt) {
        const ushort* g = Bbase + (size_t)(h * 128 + srow) * K_DIM + tt * 64 + sch * 8;
        ushort* l = lds + bb * 32768 + 16384 + h * 8192 + tid * 8;
        lds_load16(g, l);
        lds_load16(g + (size_t)64 * K_DIM, l + 4096);
    };

    // ---- prologue: stage t0 (buf0) + t1 (buf1); wait t0; pre-read F1(0)
    SA(0, 0, 0); SA(1, 0, 0); SB(0, 0, 0); SB(1, 0, 0);
    SB(0, 1, 1); SB(1, 1, 1); SA(0, 1, 1); SA(1, 1, 1);
    asm volatile("s_waitcnt vmcnt(8)" ::: "memory");   // tile0 landed; tile1 in flight
    __builtin_amdgcn_s_barrier();
    {
        const ushort* aL0 = lds + wr * 8192;
        const ushort* bL0 = lds + 16384 + (wc >> 1) * 8192 + (wc & 1) * 4096;
        #pragma unroll
        for (int i = 0; i < 4; ++i) {
            amA[i][0] = *(const short8*)(aL0 + i * 1024 + o0);
            amA[i][1] = *(const short8*)(aL0 + i * 1024 + o1);
        }
        #pragma unroll
        for (int j = 0; j < 2; ++j) {
            b01[j][0] = *(const short8*)(bL0 + j * 1024 + o0);
            b01[j][1] = *(const short8*)(bL0 + j * 1024 + o1);
        }
    }

    for (int t = 0; t < NT; ++t) {
        const int b = t & 1;
        const ushort* aL  = lds + b * 32768 + wr * 8192;
        const ushort* bL  = lds + b * 32768 + 16384 + (wc >> 1) * 8192 + (wc & 1) * 4096;
        const ushort* aLn = lds + (b ^ 1) * 32768 + wr * 8192;
        const ushort* bLn = lds + (b ^ 1) * 32768 + 16384 + (wc >> 1) * 8192 + (wc & 1) * 4096;

        // ---- P1: issue b23(t); MFMA Q1 (amA x b01, ready since last tile)
        #pragma unroll
        for (int j = 0; j < 2; ++j) {
            b23[j][0] = *(const short8*)(bL + (2 + j) * 1024 + o0);
            b23[j][1] = *(const short8*)(bL + (2 + j) * 1024 + o1);
        }
        __builtin_amdgcn_sched_barrier(0);   // keep read-issue above MFMAs
        __builtin_amdgcn_s_setprio(1);
        #pragma unroll
        for (int i = 0; i < 4; ++i)
            #pragma unroll
            for (int j = 0; j < 2; ++j) {
                acc[i][j] = MFMA16(amA[i][0], b01[j][0], acc[i][j]);
                acc[i][j] = MFMA16(amA[i][1], b01[j][1], acc[i][j]);
            }
        __builtin_amdgcn_s_setprio(0);
        __builtin_amdgcn_s_barrier();

        // ---- P2: issue amB(t); MFMA Q2 (amA x b23); boundary vmcnt(0); bar
        #pragma unroll
        for (int i = 0; i < 4; ++i) {
            amB[i][0] = *(const short8*)(aL + (4 + i) * 1024 + o0);
            amB[i][1] = *(const short8*)(aL + (4 + i) * 1024 + o1);
        }
        __builtin_amdgcn_sched_barrier(0);
        __builtin_amdgcn_s_setprio(1);
        #pragma unroll
        for (int i = 0; i < 4; ++i)
            #pragma unroll
            for (int j = 0; j < 2; ++j) {
                acc[i][2 + j] = MFMA16(amA[i][0], b23[j][0], acc[i][2 + j]);
                acc[i][2 + j] = MFMA16(amA[i][1], b23[j][1], acc[i][2 + j]);
            }
        __builtin_amdgcn_s_setprio(0);
        // drain tile t+1 staging (issued 1.5 tiles ago -> free); after the
        // barrier, buf^1 is globally valid for read-ahead.
        asm volatile("s_waitcnt vmcnt(0)" ::: "memory");
        __builtin_amdgcn_s_barrier();

        // ---- P3: issue amA(t+1) from buf^1; stage B(t+2); MFMA Q3 (amB x b23)
        if (t + 1 < NT) {
            #pragma unroll
            for (int i = 0; i < 4; ++i) {
                amA[i][0] = *(const short8*)(aLn + i * 1024 + o0);
                amA[i][1] = *(const short8*)(aLn + i * 1024 + o1);
            }
        }
        if (t + 2 < NT) { SB(0, b, t + 2); SB(1, b, t + 2); }
        __builtin_amdgcn_sched_barrier(0);
        __builtin_amdgcn_s_setprio(1);
        #pragma unroll
        for (int i = 0; i < 4; ++i)
            #pragma unroll
            for (int j = 0; j < 2; ++j) {
                acc[4 + i][2 + j] = MFMA16(amB[i][0], b23[j][0], acc[4 + i][2 + j]);
                acc[4 + i][2 + j] = MFMA16(amB[i][1], b23[j][1], acc[4 + i][2 + j]);
            }
        __builtin_amdgcn_s_setprio(0);
        __builtin_amdgcn_s_barrier();

        // ---- P4: MFMA Q4 (amB x b01, all ready); then issue b01(t+1); stage A(t+2)
        __builtin_amdgcn_s_setprio(1);
        #pragma unroll
        for (int i = 0; i < 4; ++i)
            #pragma unroll
            for (int j = 0; j < 2; ++j) {
                acc[4 + i][j] = MFMA16(amB[i][0], b01[j][0], acc[4 + i][j]);
                acc[4 + i][j] = MFMA16(amB[i][1], b01[j][1], acc[4 + i][j]);
            }
        __builtin_amdgcn_s_setprio(0);
        if (t + 1 < NT) {   // WAR on b01 keeps these below Q4 in program order
            #pragma unroll
            for (int j = 0; j < 2; ++j) {
                b01[j][0] = *(const short8*)(bLn + j * 1024 + o0);
                b01[j][1] = *(const short8*)(bLn + j * 1024 + o1);
            }
        }
        if (t + 2 < NT) { SA(0, b, t + 2); SA(1, b, t + 2); }
        __builtin_amdgcn_s_barrier();
    }

    // ---- epilogue: C/D layout col = lane&15, row = (lane>>4)*4 + reg  [m89]
    const int row0 = bm * 256 + wr * 128 + q * 4;
    const int col0 = bn * 256 + wc * 64 + r;
    #pragma unroll
    for (int i = 0; i < 8; ++i)
        #pragma unroll
        for (int j = 0; j < 4; ++j)
            #pragma unroll
            for (int v = 0; v < 4; ++v)
                C[(size_t)(row0 + i * 16 + v) * N_DIM + col0 + j * 16] = alpha * acc[i][j][v];
}

// ---------------------------------------------------------------------------
extern "C" void kernel_launch(void* const* d_in, const int* in_sizes, int n_in,
                              void* d_out, int out_size, void* d_ws, size_t ws_size,
                              hipStream_t stream) {
    const float* x = (const float*)d_in[0];  // 4*2048*4096 fp32
    const float* w = (const float*)d_in[1];  // 4096*4096 fp32
    float* out = (float*)d_out;              // 8192*4096 fp32

    char* ws = (char*)d_ws;
    double* partial = (double*)ws;                           // 16 KB (2048 doubles)
    float* alpha = (float*)(ws + 16384);                     // 4 B
    ushort* qw = (ushort*)(ws + 32768);                      // 32 MB (N x K bf16 ternary)
    ushort* xb = (ushort*)(ws + 32768 + (size_t)K_DIM * N_DIM * 2);  // 64 MB (M x K bf16)

    k_prep<<<2048, 256, 0, stream>>>(w, partial, x, xb);
    k_alpha<<<1, 256, 0, stream>>>(partial, alpha);
    k_quant<<<2048, 256, 0, stream>>>(w, alpha, qw);

    // 256x256 tiles: (8192/256)*(4096/256) = 32*16 = 512 blocks of 512 threads
    k_gemm<<<512, 512, 0, stream>>>(xb, qw, alpha, out);
}

// Round 5
// 466.290 us; speedup vs baseline: 1.0931x; 1.0844x over previous
//
#include <hip/hip_runtime.h>
#include <hip/hip_bf16.h>
#include <stdint.h>

// Problem: out[b,s,o] = alpha * sum_k x[b,s,k] * t[o,k],  t in {-1,0,+1}
// M = 4*2048 = 8192, K = 4096, N = 4096.
#define M_DIM 8192
#define K_DIM 4096
#define N_DIM 4096

typedef __attribute__((ext_vector_type(8))) short short8;
typedef __attribute__((ext_vector_type(4))) float f32x4;

// ---------------------------------------------------------------------------
// async global->LDS, 16B per lane (global_load_lds_dwordx4)
// ---------------------------------------------------------------------------
__device__ __forceinline__ void lds_load16(const ushort* g, ushort* l) {
    __builtin_amdgcn_global_load_lds(
        (const __attribute__((address_space(1))) uint32_t*)g,
        (__attribute__((address_space(3))) uint32_t*)l, 16, 0, 0);
}

__device__ __forceinline__ ushort f2bf_rne(float f) {
    uint32_t u = __float_as_uint(f);
    uint32_t r = (u + 0x7FFFu + ((u >> 16) & 1u)) >> 16;
    return (ushort)r;
}

// ---------------------------------------------------------------------------
// Pass 1 (fused): per-block partial sums of |w| (fp64, deterministic)
//                 + cast x fp32 -> bf16.  Grid-stride, 2048 blocks.
//   x is read ONCE ever -> non-temporal loads (don't pollute L2/L3; keep
//   L3 space for w / xb / qw which ARE re-read).
// ---------------------------------------------------------------------------
__global__ void k_prep(const float* __restrict__ w, double* __restrict__ partial,
                       const float* __restrict__ x, ushort* __restrict__ xb) {
    const int nth = gridDim.x * blockDim.x;
    const int gtid = blockIdx.x * blockDim.x + threadIdx.x;

    const float4* w4 = (const float4*)w;
    double s = 0.0;
    for (int i = gtid; i < (K_DIM * N_DIM) / 4; i += nth) {
        float4 v = w4[i];
        s += (double)fabsf(v.x) + (double)fabsf(v.y) + (double)fabsf(v.z) + (double)fabsf(v.w);
    }
    #pragma unroll
    for (int off = 32; off > 0; off >>= 1) s += __shfl_down(s, off, 64);
    __shared__ double sm[4];
    int lane = threadIdx.x & 63, wv = threadIdx.x >> 6;
    if (lane == 0) sm[wv] = s;
    __syncthreads();
    if (threadIdx.x == 0) partial[blockIdx.x] = sm[0] + sm[1] + sm[2] + sm[3];

    const f32x4* x4 = (const f32x4*)x;
    ushort4* xb4 = (ushort4*)xb;
    for (int i = gtid; i < (M_DIM * K_DIM) / 4; i += nth) {
        f32x4 v = __builtin_nontemporal_load(&x4[i]);   // read-once stream
        ushort4 o;
        o.x = f2bf_rne(v[0]);
        o.y = f2bf_rne(v[1]);
        o.z = f2bf_rne(v[2]);
        o.w = f2bf_rne(v[3]);
        xb4[i] = o;   // normal store: want xb L3-resident for the GEMM
    }
}

// Pass 1b: finalize alpha = mean(|w|) over 2048 partials
__global__ void k_alpha(const double* __restrict__ partial, float* __restrict__ alpha_out) {
    double s = 0.0;
    for (int i = threadIdx.x; i < 2048; i += 256) s += partial[i];
    #pragma unroll
    for (int off = 32; off > 0; off >>= 1) s += __shfl_down(s, off, 64);
    __shared__ double sm[4];
    int lane = threadIdx.x & 63, wv = threadIdx.x >> 6;
    if (lane == 0) sm[wv] = s;
    __syncthreads();
    if (threadIdx.x == 0) {
        double total = sm[0] + sm[1] + sm[2] + sm[3];
        alpha_out[0] = (float)(total * (1.0 / 16777216.0));
    }
}

// ---------------------------------------------------------------------------
// Pass 2: quantize w -> ternary {-1,0,+1} as bf16 (N x K row-major)
//   w re-read is L3-warm from k_prep; qw stored normally (GEMM re-reads it).
// ---------------------------------------------------------------------------
__global__ void k_quant(const float* __restrict__ w, const float* __restrict__ alpha_p,
                        ushort* __restrict__ qw) {
    const float thr = 0.5f * alpha_p[0];
    const int nth = gridDim.x * blockDim.x;
    const int gtid = blockIdx.x * blockDim.x + threadIdx.x;
    const float4* w4 = (const float4*)w;
    short8* q8 = (short8*)qw;
    for (int i = gtid; i < (K_DIM * N_DIM) / 8; i += nth) {
        float4 a = w4[2 * i], b = w4[2 * i + 1];
        short8 o;
        o[0] = a.x > thr ? (short)0x3F80 : (a.x < -thr ? (short)0xBF80 : (short)0);
        o[1] = a.y > thr ? (short)0x3F80 : (a.y < -thr ? (short)0xBF80 : (short)0);
        o[2] = a.z > thr ? (short)0x3F80 : (a.z < -thr ? (short)0xBF80 : (short)0);
        o[3] = a.w > thr ? (short)0x3F80 : (a.w < -thr ? (short)0xBF80 : (short)0);
        o[4] = b.x > thr ? (short)0x3F80 : (b.x < -thr ? (short)0xBF80 : (short)0);
        o[5] = b.y > thr ? (short)0x3F80 : (b.y < -thr ? (short)0xBF80 : (short)0);
        o[6] = b.z > thr ? (short)0x3F80 : (b.z < -thr ? (short)0xBF80 : (short)0);
        o[7] = b.w > thr ? (short)0x3F80 : (b.w < -thr ? (short)0xBF80 : (short)0);
        q8[i] = o;
    }
}

// ---------------------------------------------------------------------------
// Pass 3: 256x256 bf16 MFMA GEMM with READ-AHEAD software pipeline.
//   (schedule identical to round 4 — see comments there; MfmaUtil 51, 0 bank
//   conflicts, VGPR 128 + AGPR 128 = exactly at the 256-unified budget, so
//   NO new registers allowed.)
//   ROUND-5 CHANGE: non-temporal C stores. The 128MB output was streaming
//   through L2/L3 and evicting the 96MB bf16 working set (xb+qw fit L3
//   entirely, yet FETCH measured 295MB vs 96MB compulsory). nt stores
//   don't allocate in cache -> panel re-reads become L3 hits.
// ---------------------------------------------------------------------------
#define NT (K_DIM / 64)  // 64 K-tiles

#define MFMA16(a, b, c) __builtin_amdgcn_mfma_f32_16x16x32_bf16((a), (b), (c), 0, 0, 0)

__global__ __launch_bounds__(512, 2) void k_gemm(const ushort* __restrict__ A,  // M x K bf16
                                                 const ushort* __restrict__ B,  // N x K bf16
                                                 const float* __restrict__ alpha_p,
                                                 float* __restrict__ C) {
    // 128 KiB LDS. Layout (ushort offsets): buf*32768 + isB*16384 + half*8192.
    __shared__ __align__(16) ushort lds[65536];

    const int tid = threadIdx.x;
    const int lane = tid & 63;
    const int w = tid >> 6;       // 0..7
    const int wr = w >> 2;        // 0..1  M wave-group
    const int wc = w & 3;         // 0..3  N wave-group
    const int r = lane & 15, q = lane >> 4;

    // T1: XCD-aware bijective swizzle (512 blocks, 512 % 8 == 0)
    const int wg = blockIdx.x;
    const int swz = (wg & 7) * 64 + (wg >> 3);
    const int bm = swz >> 4;      // 0..31 (M tiles)
    const int bn = swz & 15;      // 0..15 (N tiles)

    float alpha = alpha_p[0];
    asm volatile("" :: "v"(alpha));

    const ushort* Abase = A + (size_t)bm * 256 * K_DIM;
    const ushort* Bbase = B + (size_t)bn * 256 * K_DIM;

    // staging: thread covers (row = tid>>3, slot = tid&7); stored logical
    // k-chunk = slot ^ (row&7) -> pre-swizzled SOURCE, lane-linear LDS dest.
    const int srow = tid >> 3;
    const int sch = (tid & 7) ^ (srow & 7);

    // read: frag (row = f*16+r, logical chunk = s*4+q) at slot (s*4+q)^(r&7)
    const int ch0 = q ^ (r & 7);
    const int o0 = r * 64 + ch0 * 8;
    const int o1 = r * 64 + (ch0 ^ 4) * 8;

    f32x4 acc[8][4] = {};           // [m-frag][n-frag]
    short8 amA[4][2], amB[4][2];    // A half-0 / half-1 fragments (this wave)
    short8 b01[2][2], b23[2][2];    // B n-frags 0-1 / 2-3

    auto SA = [&](int h, int bb, int tt) {
        const ushort* g = Abase + (size_t)(h * 128 + srow) * K_DIM + tt * 64 + sch * 8;
        ushort* l = lds + bb * 32768 + h * 8192 + tid * 8;
        lds_load16(g, l);
        lds_load16(g + (size_t)64 * K_DIM, l + 4096);
    };
    auto SB = [&](int h, int bb, int tt) {
        const ushort* g = Bbase + (size_t)(h * 128 + srow) * K_DIM + tt * 64 + sch * 8;
        ushort* l = lds + bb * 32768 + 16384 + h * 8192 + tid * 8;
        lds_load16(g, l);
        lds_load16(g + (size_t)64 * K_DIM, l + 4096);
    };

    // ---- prologue: stage t0 (buf0) + t1 (buf1); wait t0; pre-read F1(0)
    SA(0, 0, 0); SA(1, 0, 0); SB(0, 0, 0); SB(1, 0, 0);
    SB(0, 1, 1); SB(1, 1, 1); SA(0, 1, 1); SA(1, 1, 1);
    asm volatile("s_waitcnt vmcnt(8)" ::: "memory");   // tile0 landed; tile1 in flight
    __builtin_amdgcn_s_barrier();
    {
        const ushort* aL0 = lds + wr * 8192;
        const ushort* bL0 = lds + 16384 + (wc >> 1) * 8192 + (wc & 1) * 4096;
        #pragma unroll
        for (int i = 0; i < 4; ++i) {
            amA[i][0] = *(const short8*)(aL0 + i * 1024 + o0);
            amA[i][1] = *(const short8*)(aL0 + i * 1024 + o1);
        }
        #pragma unroll
        for (int j = 0; j < 2; ++j) {
            b01[j][0] = *(const short8*)(bL0 + j * 1024 + o0);
            b01[j][1] = *(const short8*)(bL0 + j * 1024 + o1);
        }
    }

    for (int t = 0; t < NT; ++t) {
        const int b = t & 1;
        const ushort* aL  = lds + b * 32768 + wr * 8192;
        const ushort* bL  = lds + b * 32768 + 16384 + (wc >> 1) * 8192 + (wc & 1) * 4096;
        const ushort* aLn = lds + (b ^ 1) * 32768 + wr * 8192;
        const ushort* bLn = lds + (b ^ 1) * 32768 + 16384 + (wc >> 1) * 8192 + (wc & 1) * 4096;

        // ---- P1: issue b23(t); MFMA Q1 (amA x b01, ready since last tile)
        #pragma unroll
        for (int j = 0; j < 2; ++j) {
            b23[j][0] = *(const short8*)(bL + (2 + j) * 1024 + o0);
            b23[j][1] = *(const short8*)(bL + (2 + j) * 1024 + o1);
        }
        __builtin_amdgcn_sched_barrier(0);   // keep read-issue above MFMAs
        __builtin_amdgcn_s_setprio(1);
        #pragma unroll
        for (int i = 0; i < 4; ++i)
            #pragma unroll
            for (int j = 0; j < 2; ++j) {
                acc[i][j] = MFMA16(amA[i][0], b01[j][0], acc[i][j]);
                acc[i][j] = MFMA16(amA[i][1], b01[j][1], acc[i][j]);
            }
        __builtin_amdgcn_s_setprio(0);
        __builtin_amdgcn_s_barrier();

        // ---- P2: issue amB(t); MFMA Q2 (amA x b23); boundary vmcnt(0); bar
        #pragma unroll
        for (int i = 0; i < 4; ++i) {
            amB[i][0] = *(const short8*)(aL + (4 + i) * 1024 + o0);
            amB[i][1] = *(const short8*)(aL + (4 + i) * 1024 + o1);
        }
        __builtin_amdgcn_sched_barrier(0);
        __builtin_amdgcn_s_setprio(1);
        #pragma unroll
        for (int i = 0; i < 4; ++i)
            #pragma unroll
            for (int j = 0; j < 2; ++j) {
                acc[i][2 + j] = MFMA16(amA[i][0], b23[j][0], acc[i][2 + j]);
                acc[i][2 + j] = MFMA16(amA[i][1], b23[j][1], acc[i][2 + j]);
            }
        __builtin_amdgcn_s_setprio(0);
        // drain tile t+1 staging (issued 1.5 tiles ago -> free); after the
        // barrier, buf^1 is globally valid for read-ahead.
        asm volatile("s_waitcnt vmcnt(0)" ::: "memory");
        __builtin_amdgcn_s_barrier();

        // ---- P3: issue amA(t+1) from buf^1; stage B(t+2); MFMA Q3 (amB x b23)
        if (t + 1 < NT) {
            #pragma unroll
            for (int i = 0; i < 4; ++i) {
                amA[i][0] = *(const short8*)(aLn + i * 1024 + o0);
                amA[i][1] = *(const short8*)(aLn + i * 1024 + o1);
            }
        }
        if (t + 2 < NT) { SB(0, b, t + 2); SB(1, b, t + 2); }
        __builtin_amdgcn_sched_barrier(0);
        __builtin_amdgcn_s_setprio(1);
        #pragma unroll
        for (int i = 0; i < 4; ++i)
            #pragma unroll
            for (int j = 0; j < 2; ++j) {
                acc[4 + i][2 + j] = MFMA16(amB[i][0], b23[j][0], acc[4 + i][2 + j]);
                acc[4 + i][2 + j] = MFMA16(amB[i][1], b23[j][1], acc[4 + i][2 + j]);
            }
        __builtin_amdgcn_s_setprio(0);
        __builtin_amdgcn_s_barrier();

        // ---- P4: MFMA Q4 (amB x b01, all ready); then issue b01(t+1); stage A(t+2)
        __builtin_amdgcn_s_setprio(1);
        #pragma unroll
        for (int i = 0; i < 4; ++i)
            #pragma unroll
            for (int j = 0; j < 2; ++j) {
                acc[4 + i][j] = MFMA16(amB[i][0], b01[j][0], acc[4 + i][j]);
                acc[4 + i][j] = MFMA16(amB[i][1], b01[j][1], acc[4 + i][j]);
            }
        __builtin_amdgcn_s_setprio(0);
        if (t + 1 < NT) {   // WAR on b01 keeps these below Q4 in program order
            #pragma unroll
            for (int j = 0; j < 2; ++j) {
                b01[j][0] = *(const short8*)(bLn + j * 1024 + o0);
                b01[j][1] = *(const short8*)(bLn + j * 1024 + o1);
            }
        }
        if (t + 2 < NT) { SA(0, b, t + 2); SA(1, b, t + 2); }
        __builtin_amdgcn_s_barrier();
    }

    // ---- epilogue: C/D layout col = lane&15, row = (lane>>4)*4 + reg  [m89]
    // Non-temporal: C is write-once, never re-read this iteration; keep it
    // out of L2/L3 so xb/qw panel re-reads stay cache-resident.
    const int row0 = bm * 256 + wr * 128 + q * 4;
    const int col0 = bn * 256 + wc * 64 + r;
    #pragma unroll
    for (int i = 0; i < 8; ++i)
        #pragma unroll
        for (int j = 0; j < 4; ++j)
            #pragma unroll
            for (int v = 0; v < 4; ++v)
                __builtin_nontemporal_store(
                    alpha * acc[i][j][v],
                    &C[(size_t)(row0 + i * 16 + v) * N_DIM + col0 + j * 16]);
}

// ---------------------------------------------------------------------------
extern "C" void kernel_launch(void* const* d_in, const int* in_sizes, int n_in,
                              void* d_out, int out_size, void* d_ws, size_t ws_size,
                              hipStream_t stream) {
    const float* x = (const float*)d_in[0];  // 4*2048*4096 fp32
    const float* w = (const float*)d_in[1];  // 4096*4096 fp32
    float* out = (float*)d_out;              // 8192*4096 fp32

    char* ws = (char*)d_ws;
    double* partial = (double*)ws;                           // 16 KB (2048 doubles)
    float* alpha = (float*)(ws + 16384);                     // 4 B
    ushort* qw = (ushort*)(ws + 32768);                      // 32 MB (N x K bf16 ternary)
    ushort* xb = (ushort*)(ws + 32768 + (size_t)K_DIM * N_DIM * 2);  // 64 MB (M x K bf16)

    k_prep<<<2048, 256, 0, stream>>>(w, partial, x, xb);
    k_alpha<<<1, 256, 0, stream>>>(partial, alpha);
    k_quant<<<2048, 256, 0, stream>>>(w, alpha, qw);

    // 256x256 tiles: (8192/256)*(4096/256) = 32*16 = 512 blocks of 512 threads
    k_gemm<<<512, 512, 0, stream>>>(xb, qw, alpha, out);
}